// Round 7
// baseline (370.101 us; speedup 1.0000x reference)
//
#include <hip/hip_runtime.h>
#include <hip/hip_bf16.h>
#include <cstdint>

#define NN 12288

typedef __attribute__((ext_vector_type(8))) short bfrag8;
typedef __attribute__((ext_vector_type(4))) float f32x4;
typedef __attribute__((ext_vector_type(4))) uint16_t u16x4;
typedef __attribute__((ext_vector_type(8))) uint16_t u16x8;

__device__ __forceinline__ uint16_t f2bf_rtn(float f) {
    uint32_t u = __float_as_uint(f);
    return (uint16_t)((u + 0x7fffu + ((u >> 16) & 1u)) >> 16);
}
// hi = truncated bf16 (residual exact), lo = RTN bf16 of residual
__device__ __forceinline__ void split_bf(float f, uint16_t& hb, uint16_t& lb) {
    uint32_t u = __float_as_uint(f);
    hb = (uint16_t)(u >> 16);
    float fr = f - __uint_as_float(u & 0xffff0000u);
    lb = f2bf_rtn(fr);
}

// Workgroup barrier that does NOT drain vmcnt (global prefetch loads stay in
// flight across the barrier; only LDS ops are fenced).
__device__ __forceinline__ void lds_sync() {
    asm volatile("s_waitcnt lgkmcnt(0)" ::: "memory");
    __builtin_amdgcn_s_barrier();
    asm volatile("" ::: "memory");
}

// ---------------------------------------------------------------------------
// Transpose four [192][64] weights into [64][192] in one launch.
__global__ void wt4_kernel(const float* __restrict__ w0, const float* __restrict__ w1,
                           const float* __restrict__ w2, const float* __restrict__ w3,
                           float* __restrict__ o0, float* __restrict__ o1,
                           float* __restrict__ o2, float* __restrict__ o3) {
    const float* w; float* o;
    switch (blockIdx.y) {
        case 0: w = w0; o = o0; break;
        case 1: w = w1; o = o1; break;
        case 2: w = w2; o = o2; break;
        default: w = w3; o = o3; break;
    }
    int i = blockIdx.x * 256 + threadIdx.x;
    if (i < 192 * 64) {
        int r = i / 64, k = i % 64;
        o[k * 192 + r] = w[i];
    }
}

// ---------------------------------------------------------------------------
// B = X @ W (fp32) -> tile-contiguous packed bf16 hi/lo:
//   Bpk[(k>>6)*8192 + part*4096 + (((k>>3)&7)*64 + c)*8 + (k&7)]
__global__ void __launch_bounds__(256) xw_kernel(const float* __restrict__ X,
                                                 const float* __restrict__ W,
                                                 uint16_t* __restrict__ Bpk) {
    __shared__ __align__(16) float sW[64 * 65];
    __shared__ __align__(16) float sX[64 * 65];
    const int t = threadIdx.x;
    const int rb = blockIdx.x * 64;
    for (int i = t; i < 4096; i += 256) {
        int rr = i >> 6, cc = i & 63;
        sW[rr * 65 + cc] = W[i];
        sX[rr * 65 + cc] = X[(size_t)rb * 64 + i];
    }
    __syncthreads();
    const int r = t & 63;
    const int c0 = (t >> 6) * 16;
    float acc[16];
#pragma unroll
    for (int i = 0; i < 16; i++) acc[i] = 0.f;
    for (int k = 0; k < 64; k++) {
        float xv = sX[r * 65 + k];
#pragma unroll
        for (int i = 0; i < 16; i++) acc[i] += xv * sW[k * 65 + c0 + i];
    }
    const int j = rb + r;
    const size_t base = (size_t)(j >> 6) * 8192 + (size_t)((j >> 3) & 7) * 512 + (j & 7);
#pragma unroll
    for (int i = 0; i < 16; i++) {
        uint16_t hb, lb;
        split_bf(acc[i], hb, lb);
        size_t idx = base + (size_t)(c0 + i) * 8;
        Bpk[idx] = hb;
        Bpk[idx + 4096] = lb;
    }
}

// ---------------------------------------------------------------------------
// partial[kc] = adj[:, kchunk] @ B[kchunk, :]   (bf16 hi/lo, 3-MFMA)
// grid (192, KSPLIT), block 256 (4 waves). Tile: 64 rows x 64 cols x 64 k.
// A: per-lane direct global loads (no LDS round-trip — each A fragment is
//    consumed by exactly one lane). Converted hi/lo in-register.
// B: shared by all waves -> double-buffered LDS (2 x 16 KB), ONE lgkm-only
//    barrier per tile; B global loads (L2-resident) prefetched in registers.
__global__ void __launch_bounds__(256, 2) spmm_kernel(
    const float* __restrict__ adj,
    const uint16_t* __restrict__ Bpk,
    float* __restrict__ partial,
    int ktiles, int rev) {
    __shared__ __align__(16) uint16_t sB0[8192];   // tile buf 0: hi(4096)+lo(4096)
    __shared__ __align__(16) uint16_t sB1[8192];   // tile buf 1
    const int t = threadIdx.x;
    const int rb = blockIdx.x;
    const int kc = blockIdx.y;
    const int tile0 = kc * ktiles;
    const int wave = t >> 6, lane = t & 63;
    const int arow = wave * 16 + (lane & 15);
    const int kq = lane >> 4;
    const float* arp = adj + ((size_t)(rb * 64 + arow)) * NN;  // lane's row base

    f32x4 acc[4];
#pragma unroll
    for (int i = 0; i < 4; i++) {
        acc[i][0] = 0.f; acc[i][1] = 0.f; acc[i][2] = 0.f; acc[i][3] = 0.f;
    }

    auto tid2glob = [&](int i) { return tile0 + (rev ? (ktiles - 1 - i) : i); };

    // --- A: per-lane 16 floats/tile: k = ks*32 + kq*8 .. +8, ks in {0,1}
    f32x4 aC[4], aN[4];   // current / next tile A values
    auto load_A = [&](int tl, f32x4 (&a)[4]) {
        const float* p = arp + (size_t)tid2glob(tl) * 64 + kq * 8;
        a[0] = *(const f32x4*)(p);
        a[1] = *(const f32x4*)(p + 4);
        a[2] = *(const f32x4*)(p + 32);
        a[3] = *(const f32x4*)(p + 36);
    };
    bfrag8 ahi[2], alo[2];
    auto conv_A = [&](f32x4 (&a)[4]) {
#pragma unroll
        for (int ks = 0; ks < 2; ++ks) {
#pragma unroll
            for (int h = 0; h < 2; ++h) {
#pragma unroll
                for (int q = 0; q < 4; ++q) {
                    uint16_t hb, lb;
                    split_bf(a[ks * 2 + h][q], hb, lb);
                    ahi[ks][h * 4 + q] = (short)hb;
                    alo[ks][h * 4 + q] = (short)lb;
                }
            }
        }
    };

    // --- B: reg prefetch -> LDS double buffer
    u16x8 breg[4];
    auto load_B = [&](int tl) {
        const u16x8* bsrc = (const u16x8*)(Bpk + (size_t)tid2glob(tl) * 8192);
#pragma unroll
        for (int i = 0; i < 4; ++i) breg[i] = bsrc[i * 256 + t];
    };
    auto stage_B = [&](uint16_t* sB) {
#pragma unroll
        for (int i = 0; i < 4; ++i) ((u16x8*)sB)[i * 256 + t] = breg[i];
    };

    auto compute = [&](const uint16_t* sB) {
#pragma unroll
        for (int ks = 0; ks < 2; ++ks) {
            const int bko = (ks * 4 + kq) * 512;
#pragma unroll
            for (int ct = 0; ct < 4; ++ct) {
                int col = ct * 16 + (lane & 15);
                bfrag8 bh = *(const bfrag8*)&sB[bko + col * 8];
                bfrag8 bl = *(const bfrag8*)&sB[4096 + bko + col * 8];
                acc[ct] = __builtin_amdgcn_mfma_f32_16x16x32_bf16(ahi[ks], bh, acc[ct], 0, 0, 0);
                acc[ct] = __builtin_amdgcn_mfma_f32_16x16x32_bf16(alo[ks], bh, acc[ct], 0, 0, 0);
                acc[ct] = __builtin_amdgcn_mfma_f32_16x16x32_bf16(ahi[ks], bl, acc[ct], 0, 0, 0);
            }
        }
    };

    // prologue
    load_B(0);
    load_A(0, aC);
    load_A(1, aN);

    for (int tl = 0; tl < ktiles; tl += 2) {
        // even tile -> sB0
        stage_B(sB0);                       // counted vmcnt wait on breg
        if (tl + 1 < ktiles) load_B(tl + 1);
        lds_sync();                         // one barrier; vmcnt NOT drained
        conv_A(aC);
        if (tl + 2 < ktiles) load_A(tl + 2, aC);
        compute(sB0);
        // odd tile -> sB1
        stage_B(sB1);
        if (tl + 2 < ktiles) load_B(tl + 2);
        lds_sync();
        conv_A(aN);
        if (tl + 3 < ktiles) load_A(tl + 3, aN);
        compute(sB1);
    }

    // epilogue: C layout (m89-verified): col = lane&15, row = (lane>>4)*4 + reg
    float* pout = partial + (size_t)kc * ((size_t)NN * 64);
    const int orow = rb * 64 + wave * 16 + (lane >> 4) * 4;
    const int ocol = lane & 15;
#pragma unroll
    for (int ct = 0; ct < 4; ++ct) {
#pragma unroll
        for (int r = 0; r < 4; ++r) {
            pout[(size_t)(orow + r) * 64 + ct * 16 + ocol] = acc[ct][r];
        }
    }
}

// ---------------------------------------------------------------------------
// Fused: m = sum(partials); GRUCell(m, x); relu; write fp32 output.
__global__ void __launch_bounds__(256, 4) gru_kernel(
    const float* __restrict__ partial, int ksplit,
    const float* __restrict__ Xin,
    const float* __restrict__ wtih,  // [64][192]
    const float* __restrict__ wthh,  // [64][192]
    const float* __restrict__ bih,
    const float* __restrict__ bhh,
    float* __restrict__ hout) {
    __shared__ __align__(16) float sM[32 * 64];
    __shared__ __align__(16) float sX[32 * 64];
    const int t = threadIdx.x;
    const int nb = blockIdx.x * 32;
    {
        size_t g0 = (size_t)nb * 64 + (size_t)t * 8;
        f32x4 s0, s1;
        {
            const f32x4* p0 = (const f32x4*)(partial + g0);
            s0 = p0[0]; s1 = p0[1];
        }
        for (int p = 1; p < ksplit; p++) {
            const f32x4* pp = (const f32x4*)(partial + (size_t)p * ((size_t)NN * 64) + g0);
            f32x4 a = pp[0], b = pp[1];
#pragma unroll
            for (int q = 0; q < 4; q++) { s0[q] += a[q]; s1[q] += b[q]; }
        }
        *(f32x4*)&sM[t * 8] = s0;
        *(f32x4*)&sM[t * 8 + 4] = s1;
        const f32x4* px = (const f32x4*)(Xin + g0);
        *(f32x4*)&sX[t * 8] = px[0];
        *(f32x4*)&sX[t * 8 + 4] = px[1];
    }
    __syncthreads();
    const int wave = t >> 6, lane = t & 63;
    const int nodebase = wave * 8;
    float a_ir[8], a_iz[8], a_in[8], a_hr[8], a_hz[8], a_hn[8];
#pragma unroll
    for (int n = 0; n < 8; n++) {
        a_ir[n] = 0.f; a_iz[n] = 0.f; a_in[n] = 0.f;
        a_hr[n] = 0.f; a_hz[n] = 0.f; a_hn[n] = 0.f;
    }
    for (int k = 0; k < 64; k++) {
        float w0 = wtih[k * 192 + lane];
        float w1 = wtih[k * 192 + 64 + lane];
        float w2 = wtih[k * 192 + 128 + lane];
        float w3 = wthh[k * 192 + lane];
        float w4 = wthh[k * 192 + 64 + lane];
        float w5 = wthh[k * 192 + 128 + lane];
#pragma unroll
        for (int n = 0; n < 8; n++) {
            float mv = sM[(nodebase + n) * 64 + k];
            float xv = sX[(nodebase + n) * 64 + k];
            a_ir[n] += w0 * mv; a_iz[n] += w1 * mv; a_in[n] += w2 * mv;
            a_hr[n] += w3 * xv; a_hz[n] += w4 * xv; a_hn[n] += w5 * xv;
        }
    }
    const float b0 = bih[lane], b1 = bih[64 + lane], b2 = bih[128 + lane];
    const float b3 = bhh[lane], b4 = bhh[64 + lane], b5 = bhh[128 + lane];
#pragma unroll
    for (int n = 0; n < 8; n++) {
        float ir = a_ir[n] + b0, iz = a_iz[n] + b1, inn = a_in[n] + b2;
        float hr = a_hr[n] + b3, hz = a_hz[n] + b4, hn = a_hn[n] + b5;
        float r = 1.f / (1.f + __expf(-(ir + hr)));
        float z = 1.f / (1.f + __expf(-(iz + hz)));
        float nt = tanhf(inn + r * hn);
        float xv = sX[(nodebase + n) * 64 + lane];
        float o = (1.f - z) * nt + z * xv;
        o = fmaxf(o, 0.f);
        size_t oi = (size_t)(nb + nodebase + n) * 64 + lane;
        hout[oi] = o;
    }
}

// ---------------------------------------------------------------------------
extern "C" void kernel_launch(void* const* d_in, const int* in_sizes, int n_in,
                              void* d_out, int out_size, void* d_ws, size_t ws_size,
                              hipStream_t stream) {
    const float* x    = (const float*)d_in[0];
    const float* adj  = (const float*)d_in[1];
    const float* W1   = (const float*)d_in[2];
    const float* wih1 = (const float*)d_in[3];
    const float* whh1 = (const float*)d_in[4];
    const float* bih1 = (const float*)d_in[5];
    const float* bhh1 = (const float*)d_in[6];
    const float* W2   = (const float*)d_in[7];
    const float* wih2 = (const float*)d_in[8];
    const float* whh2 = (const float*)d_in[9];
    const float* bih2 = (const float*)d_in[10];
    const float* bhh2 = (const float*)d_in[11];
    float* out = (float*)d_out;   // reference output dtype is float32

    char* p = (char*)d_ws;
    float* wtih1 = (float*)p; p += (size_t)192 * 64 * 4;
    float* wthh1 = (float*)p; p += (size_t)192 * 64 * 4;
    float* wtih2 = (float*)p; p += (size_t)192 * 64 * 4;
    float* wthh2 = (float*)p; p += (size_t)192 * 64 * 4;
    float* h     = (float*)p; p += (size_t)NN * 64 * 4;
    uint16_t* Bpk = (uint16_t*)p; p += (size_t)NN * 64 * 2 * 2;  // hi+lo packed
    float* partial = (float*)p;
    size_t used = (size_t)(p - (char*)d_ws);
    size_t unit = (size_t)NN * 64 * 4;

    int ksplit = 1;
    const int opts[3] = {4, 2, 1};
    for (int i = 0; i < 3; i++) {
        if (used + (size_t)opts[i] * unit <= ws_size) { ksplit = opts[i]; break; }
    }
    int ktiles = 192 / ksplit;

    wt4_kernel<<<dim3(48, 4), 256, 0, stream>>>(wih1, whh1, wih2, whh2,
                                                wtih1, wthh1, wtih2, wthh2);

    // layer 1 (forward K order)
    xw_kernel<<<192, 256, 0, stream>>>(x, W1, Bpk);
    spmm_kernel<<<dim3(192, ksplit), 256, 0, stream>>>(adj, Bpk, partial, ktiles, 0);
    gru_kernel<<<384, 256, 0, stream>>>(partial, ksplit, x, wtih1, wthh1, bih1, bhh1, h);
    // layer 2 (reverse K order — boustrophedon: reuse adj tail still in L3)
    xw_kernel<<<192, 256, 0, stream>>>(h, W2, Bpk);
    spmm_kernel<<<dim3(192, ksplit), 256, 0, stream>>>(adj, Bpk, partial, ktiles, 1);
    gru_kernel<<<384, 256, 0, stream>>>(partial, ksplit, h, wtih2, wthh2, bih2, bhh2, out);
}

// Round 8
// 349.227 us; speedup vs baseline: 1.0598x; 1.0598x over previous
//
#include <hip/hip_runtime.h>
#include <hip/hip_bf16.h>
#include <cstdint>

#define NN 12288

typedef __attribute__((ext_vector_type(8))) short bfrag8;
typedef __attribute__((ext_vector_type(4))) float f32x4;
typedef __attribute__((ext_vector_type(4))) uint16_t u16x4;
typedef __attribute__((ext_vector_type(8))) uint16_t u16x8;
typedef __attribute__((ext_vector_type(2))) uint32_t u32x2;

__device__ __forceinline__ uint16_t f2bf_rtn(float f) {
    uint32_t u = __float_as_uint(f);
    return (uint16_t)((u + 0x7fffu + ((u >> 16) & 1u)) >> 16);
}
// hi = truncated bf16 (residual exact), lo = RTN bf16 of residual
__device__ __forceinline__ void split_bf(float f, uint16_t& hb, uint16_t& lb) {
    uint32_t u = __float_as_uint(f);
    hb = (uint16_t)(u >> 16);
    float fr = f - __uint_as_float(u & 0xffff0000u);
    lb = f2bf_rtn(fr);
}

// Packed hi/lo split of 4 floats using v_cvt_pk_bf16_f32 via the official
// intrinsic (m240: do NOT hand-write the asm). hi = RNE bf16 pair (packed),
// residual fr = f - hi is exactly representable; lo = RNE(fr) pair.
// ~3 VALU ops/elem vs ~8 for the scalar split.
__device__ __forceinline__ void split4_pk(const f32x4& f, u32x2& hi, u32x2& lo) {
    float2 p01; p01.x = f[0]; p01.y = f[1];
    float2 p23; p23.x = f[2]; p23.y = f[3];
    __hip_bfloat162 h01 = __float22bfloat162_rn(p01);
    __hip_bfloat162 h23 = __float22bfloat162_rn(p23);
    uint32_t uh01 = *reinterpret_cast<uint32_t*>(&h01);
    uint32_t uh23 = *reinterpret_cast<uint32_t*>(&h23);
    float2 r01, r23;
    r01.x = f[0] - __uint_as_float(uh01 << 16);
    r01.y = f[1] - __uint_as_float(uh01 & 0xffff0000u);
    r23.x = f[2] - __uint_as_float(uh23 << 16);
    r23.y = f[3] - __uint_as_float(uh23 & 0xffff0000u);
    __hip_bfloat162 l01 = __float22bfloat162_rn(r01);
    __hip_bfloat162 l23 = __float22bfloat162_rn(r23);
    hi[0] = uh01; hi[1] = uh23;
    lo[0] = *reinterpret_cast<uint32_t*>(&l01);
    lo[1] = *reinterpret_cast<uint32_t*>(&l23);
}

// Workgroup barrier that does NOT drain vmcnt (keeps global prefetch loads
// in flight across the barrier; only LDS ops are fenced).
__device__ __forceinline__ void lds_sync() {
    asm volatile("s_waitcnt lgkmcnt(0)" ::: "memory");
    __builtin_amdgcn_s_barrier();
    asm volatile("" ::: "memory");
}

// ---------------------------------------------------------------------------
// Transpose four [192][64] weights into [64][192] in one launch.
__global__ void wt4_kernel(const float* __restrict__ w0, const float* __restrict__ w1,
                           const float* __restrict__ w2, const float* __restrict__ w3,
                           float* __restrict__ o0, float* __restrict__ o1,
                           float* __restrict__ o2, float* __restrict__ o3) {
    const float* w; float* o;
    switch (blockIdx.y) {
        case 0: w = w0; o = o0; break;
        case 1: w = w1; o = o1; break;
        case 2: w = w2; o = o2; break;
        default: w = w3; o = o3; break;
    }
    int i = blockIdx.x * 256 + threadIdx.x;
    if (i < 192 * 64) {
        int r = i / 64, k = i % 64;
        o[k * 192 + r] = w[i];
    }
}

// ---------------------------------------------------------------------------
// B = X @ W (fp32) -> tile-contiguous packed bf16 hi/lo:
//   Bpk[(k>>6)*8192 + part*4096 + (((k>>3)&7)*64 + c)*8 + (k&7)]
__global__ void __launch_bounds__(256) xw_kernel(const float* __restrict__ X,
                                                 const float* __restrict__ W,
                                                 uint16_t* __restrict__ Bpk) {
    __shared__ __align__(16) float sW[64 * 65];
    __shared__ __align__(16) float sX[64 * 65];
    const int t = threadIdx.x;
    const int rb = blockIdx.x * 64;
    for (int i = t; i < 4096; i += 256) {
        int rr = i >> 6, cc = i & 63;
        sW[rr * 65 + cc] = W[i];
        sX[rr * 65 + cc] = X[(size_t)rb * 64 + i];
    }
    __syncthreads();
    const int r = t & 63;
    const int c0 = (t >> 6) * 16;
    float acc[16];
#pragma unroll
    for (int i = 0; i < 16; i++) acc[i] = 0.f;
    for (int k = 0; k < 64; k++) {
        float xv = sX[r * 65 + k];
#pragma unroll
        for (int i = 0; i < 16; i++) acc[i] += xv * sW[k * 65 + c0 + i];
    }
    const int j = rb + r;
    const size_t base = (size_t)(j >> 6) * 8192 + (size_t)((j >> 3) & 7) * 512 + (j & 7);
#pragma unroll
    for (int i = 0; i < 16; i++) {
        uint16_t hb, lb;
        split_bf(acc[i], hb, lb);
        size_t idx = base + (size_t)(c0 + i) * 8;
        Bpk[idx] = hb;
        Bpk[idx + 4096] = lb;
    }
}

// ---------------------------------------------------------------------------
// partial[kc] = adj[:, kchunk] @ B[kchunk, :]   (bf16 hi/lo, 3-MFMA)
// grid (192, KSPLIT), block 256 (4 waves). Tile: 64 rows x 64 cols x 64 k.
// Depth-2 register prefetch across raw (non-vmcnt-draining) barriers.
// A in LDS with 16B-granular XOR swizzle (stride 128B): total LDS = 32 KB.
__global__ void __launch_bounds__(256, 2) spmm_kernel(
    const float* __restrict__ adj,
    const uint16_t* __restrict__ Bpk,
    float* __restrict__ partial,
    int ktiles, int rev) {
    __shared__ __align__(16) uint16_t sAhi[4096];
    __shared__ __align__(16) uint16_t sAlo[4096];
    __shared__ __align__(16) uint16_t sB[8192];   // hi(4096) + lo(4096)
    const int t = threadIdx.x;
    const int rb = blockIdx.x;
    const int kc = blockIdx.y;
    const int tile0 = kc * ktiles;
    const int wave = t >> 6, lane = t & 63;
    const int srow16 = t >> 4;        // 0..15
    const int skk = (t & 15) * 4;     // 0..60
    const float* aptr = adj + (size_t)rb * 64 * NN;
    const int arow = wave * 16 + (lane & 15);
    const int kq = lane >> 4;

    f32x4 acc[4];
#pragma unroll
    for (int i = 0; i < 4; i++) {
        acc[i][0] = 0.f; acc[i][1] = 0.f; acc[i][2] = 0.f; acc[i][3] = 0.f;
    }

    f32x4 lA0[4], lA1[4];
    u16x8 lB0[4], lB1[4];

    auto tid2glob = [&](int i) { return tile0 + (rev ? (ktiles - 1 - i) : i); };

    auto load_tile = [&](int tl, f32x4 (&lA)[4], u16x8 (&lB)[4]) {
        const float* ap = aptr + (size_t)tid2glob(tl) * 64;
#pragma unroll
        for (int it = 0; it < 4; ++it) {
            int row = it * 16 + srow16;
            lA[it] = *(const f32x4*)(ap + (size_t)row * NN + skk);
        }
        const u16x8* bsrc = (const u16x8*)(Bpk + (size_t)tid2glob(tl) * 8192);
#pragma unroll
        for (int i = 0; i < 4; ++i) lB[i] = bsrc[i * 256 + t];
    };

    auto stage_tile = [&](f32x4 (&lA)[4], u16x8 (&lB)[4]) {
#pragma unroll
        for (int it = 0; it < 4; ++it) {
            int row = it * 16 + srow16;
            u32x2 hi, lo;
            split4_pk(lA[it], hi, lo);
            int off = row * 128 + (((skk >> 3) ^ (row & 7)) << 4) + ((skk & 7) << 1);
            *(u32x2*)((char*)sAhi + off) = hi;
            *(u32x2*)((char*)sAlo + off) = lo;
        }
#pragma unroll
        for (int i = 0; i < 4; ++i) ((u16x8*)sB)[i * 256 + t] = lB[i];
    };

    auto compute_tile = [&]() {
#pragma unroll
        for (int ks = 0; ks < 2; ++ks) {
            const int chunk = ks * 4 + kq;
            const int aoff = arow * 128 + ((chunk ^ (arow & 7)) << 4);
            bfrag8 ahi = *(const bfrag8*)((const char*)sAhi + aoff);
            bfrag8 alo = *(const bfrag8*)((const char*)sAlo + aoff);
            const int bko = chunk * 512;
#pragma unroll
            for (int ct = 0; ct < 4; ++ct) {
                int col = ct * 16 + (lane & 15);
                bfrag8 bh = *(const bfrag8*)&sB[bko + col * 8];
                bfrag8 bl = *(const bfrag8*)&sB[4096 + bko + col * 8];
                acc[ct] = __builtin_amdgcn_mfma_f32_16x16x32_bf16(ahi, bh, acc[ct], 0, 0, 0);
                acc[ct] = __builtin_amdgcn_mfma_f32_16x16x32_bf16(alo, bh, acc[ct], 0, 0, 0);
                acc[ct] = __builtin_amdgcn_mfma_f32_16x16x32_bf16(ahi, bl, acc[ct], 0, 0, 0);
            }
        }
    };

    // prologue: two tiles in flight
    load_tile(0, lA0, lB0);
    load_tile(1, lA1, lB1);

    for (int tl = 0; tl < ktiles; tl += 2) {
        // phase A (even tile, register buffer 0)
        lds_sync();                       // prev compute done; LDS free
        stage_tile(lA0, lB0);             // counted vmcnt wait on buf0 loads only
        lds_sync();                       // LDS visible; vmcnt NOT drained
        if (tl + 2 < ktiles) load_tile(tl + 2, lA0, lB0);
        compute_tile();
        // phase B (odd tile, register buffer 1)
        lds_sync();
        stage_tile(lA1, lB1);
        lds_sync();
        if (tl + 3 < ktiles) load_tile(tl + 3, lA1, lB1);
        compute_tile();
    }

    // epilogue: C layout (m89-verified): col = lane&15, row = (lane>>4)*4 + reg
    float* pout = partial + (size_t)kc * ((size_t)NN * 64);
    const int orow = rb * 64 + wave * 16 + (lane >> 4) * 4;
    const int ocol = lane & 15;
#pragma unroll
    for (int ct = 0; ct < 4; ++ct) {
#pragma unroll
        for (int r = 0; r < 4; ++r) {
            pout[(size_t)(orow + r) * 64 + ct * 16 + ocol] = acc[ct][r];
        }
    }
}

// ---------------------------------------------------------------------------
// Fused: m = sum(partials); GRUCell(m, x); relu; write fp32 output.
__global__ void __launch_bounds__(256, 4) gru_kernel(
    const float* __restrict__ partial, int ksplit,
    const float* __restrict__ Xin,
    const float* __restrict__ wtih,  // [64][192]
    const float* __restrict__ wthh,  // [64][192]
    const float* __restrict__ bih,
    const float* __restrict__ bhh,
    float* __restrict__ hout) {
    __shared__ __align__(16) float sM[32 * 64];
    __shared__ __align__(16) float sX[32 * 64];
    const int t = threadIdx.x;
    const int nb = blockIdx.x * 32;
    {
        size_t g0 = (size_t)nb * 64 + (size_t)t * 8;
        f32x4 s0, s1;
        {
            const f32x4* p0 = (const f32x4*)(partial + g0);
            s0 = p0[0]; s1 = p0[1];
        }
        for (int p = 1; p < ksplit; p++) {
            const f32x4* pp = (const f32x4*)(partial + (size_t)p * ((size_t)NN * 64) + g0);
            f32x4 a = pp[0], b = pp[1];
#pragma unroll
            for (int q = 0; q < 4; q++) { s0[q] += a[q]; s1[q] += b[q]; }
        }
        *(f32x4*)&sM[t * 8] = s0;
        *(f32x4*)&sM[t * 8 + 4] = s1;
        const f32x4* px = (const f32x4*)(Xin + g0);
        *(f32x4*)&sX[t * 8] = px[0];
        *(f32x4*)&sX[t * 8 + 4] = px[1];
    }
    __syncthreads();
    const int wave = t >> 6, lane = t & 63;
    const int nodebase = wave * 8;
    float a_ir[8], a_iz[8], a_in[8], a_hr[8], a_hz[8], a_hn[8];
#pragma unroll
    for (int n = 0; n < 8; n++) {
        a_ir[n] = 0.f; a_iz[n] = 0.f; a_in[n] = 0.f;
        a_hr[n] = 0.f; a_hz[n] = 0.f; a_hn[n] = 0.f;
    }
    for (int k = 0; k < 64; k++) {
        float w0 = wtih[k * 192 + lane];
        float w1 = wtih[k * 192 + 64 + lane];
        float w2 = wtih[k * 192 + 128 + lane];
        float w3 = wthh[k * 192 + lane];
        float w4 = wthh[k * 192 + 64 + lane];
        float w5 = wthh[k * 192 + 128 + lane];
#pragma unroll
        for (int n = 0; n < 8; n++) {
            float mv = sM[(nodebase + n) * 64 + k];
            float xv = sX[(nodebase + n) * 64 + k];
            a_ir[n] += w0 * mv; a_iz[n] += w1 * mv; a_in[n] += w2 * mv;
            a_hr[n] += w3 * xv; a_hz[n] += w4 * xv; a_hn[n] += w5 * xv;
        }
    }
    const float b0 = bih[lane], b1 = bih[64 + lane], b2 = bih[128 + lane];
    const float b3 = bhh[lane], b4 = bhh[64 + lane], b5 = bhh[128 + lane];
#pragma unroll
    for (int n = 0; n < 8; n++) {
        float ir = a_ir[n] + b0, iz = a_iz[n] + b1, inn = a_in[n] + b2;
        float hr = a_hr[n] + b3, hz = a_hz[n] + b4, hn = a_hn[n] + b5;
        float r = 1.f / (1.f + __expf(-(ir + hr)));
        float z = 1.f / (1.f + __expf(-(iz + hz)));
        float nt = tanhf(inn + r * hn);
        float xv = sX[(nodebase + n) * 64 + lane];
        float o = (1.f - z) * nt + z * xv;
        o = fmaxf(o, 0.f);
        size_t oi = (size_t)(nb + nodebase + n) * 64 + lane;
        hout[oi] = o;
    }
}

// ---------------------------------------------------------------------------
extern "C" void kernel_launch(void* const* d_in, const int* in_sizes, int n_in,
                              void* d_out, int out_size, void* d_ws, size_t ws_size,
                              hipStream_t stream) {
    const float* x    = (const float*)d_in[0];
    const float* adj  = (const float*)d_in[1];
    const float* W1   = (const float*)d_in[2];
    const float* wih1 = (const float*)d_in[3];
    const float* whh1 = (const float*)d_in[4];
    const float* bih1 = (const float*)d_in[5];
    const float* bhh1 = (const float*)d_in[6];
    const float* W2   = (const float*)d_in[7];
    const float* wih2 = (const float*)d_in[8];
    const float* whh2 = (const float*)d_in[9];
    const float* bih2 = (const float*)d_in[10];
    const float* bhh2 = (const float*)d_in[11];
    float* out = (float*)d_out;   // reference output dtype is float32

    char* p = (char*)d_ws;
    float* wtih1 = (float*)p; p += (size_t)192 * 64 * 4;
    float* wthh1 = (float*)p; p += (size_t)192 * 64 * 4;
    float* wtih2 = (float*)p; p += (size_t)192 * 64 * 4;
    float* wthh2 = (float*)p; p += (size_t)192 * 64 * 4;
    float* h     = (float*)p; p += (size_t)NN * 64 * 4;
    uint16_t* Bpk = (uint16_t*)p; p += (size_t)NN * 64 * 2 * 2;  // hi+lo packed
    float* partial = (float*)p;
    size_t used = (size_t)(p - (char*)d_ws);
    size_t unit = (size_t)NN * 64 * 4;

    int ksplit = 1;
    const int opts[3] = {4, 2, 1};
    for (int i = 0; i < 3; i++) {
        if (used + (size_t)opts[i] * unit <= ws_size) { ksplit = opts[i]; break; }
    }
    int ktiles = 192 / ksplit;

    wt4_kernel<<<dim3(48, 4), 256, 0, stream>>>(wih1, whh1, wih2, whh2,
                                                wtih1, wthh1, wtih2, wthh2);

    // layer 1 (forward K order)
    xw_kernel<<<192, 256, 0, stream>>>(x, W1, Bpk);
    spmm_kernel<<<dim3(192, ksplit), 256, 0, stream>>>(adj, Bpk, partial, ktiles, 0);
    gru_kernel<<<384, 256, 0, stream>>>(partial, ksplit, x, wtih1, wthh1, bih1, bhh1, h);
    // layer 2 (reverse K order — boustrophedon: reuse adj tail still in L3)
    xw_kernel<<<192, 256, 0, stream>>>(h, W2, Bpk);
    spmm_kernel<<<dim3(192, ksplit), 256, 0, stream>>>(adj, Bpk, partial, ktiles, 1);
    gru_kernel<<<384, 256, 0, stream>>>(partial, ksplit, h, wtih2, wthh2, bih2, bhh2, out);
}

// Round 9
// 334.666 us; speedup vs baseline: 1.1059x; 1.0435x over previous
//
#include <hip/hip_runtime.h>
#include <hip/hip_bf16.h>
#include <cstdint>

#define NN 12288

typedef __attribute__((ext_vector_type(8))) short bfrag8;
typedef __attribute__((ext_vector_type(4))) float f32x4;
typedef __attribute__((ext_vector_type(4))) uint16_t u16x4;
typedef __attribute__((ext_vector_type(8))) uint16_t u16x8;
typedef __attribute__((ext_vector_type(2))) uint32_t u32x2;

__device__ __forceinline__ uint16_t f2bf_rtn(float f) {
    uint32_t u = __float_as_uint(f);
    return (uint16_t)((u + 0x7fffu + ((u >> 16) & 1u)) >> 16);
}
__device__ __forceinline__ void split_bf(float f, uint16_t& hb, uint16_t& lb) {
    uint32_t u = __float_as_uint(f);
    hb = (uint16_t)(u >> 16);
    float fr = f - __uint_as_float(u & 0xffff0000u);
    lb = f2bf_rtn(fr);
}

// Packed hi/lo split of 4 floats (v_cvt_pk_bf16_f32 via official intrinsic).
__device__ __forceinline__ void split4_pk(const f32x4& f, u32x2& hi, u32x2& lo) {
    float2 p01; p01.x = f[0]; p01.y = f[1];
    float2 p23; p23.x = f[2]; p23.y = f[3];
    __hip_bfloat162 h01 = __float22bfloat162_rn(p01);
    __hip_bfloat162 h23 = __float22bfloat162_rn(p23);
    uint32_t uh01 = *reinterpret_cast<uint32_t*>(&h01);
    uint32_t uh23 = *reinterpret_cast<uint32_t*>(&h23);
    float2 r01, r23;
    r01.x = f[0] - __uint_as_float(uh01 << 16);
    r01.y = f[1] - __uint_as_float(uh01 & 0xffff0000u);
    r23.x = f[2] - __uint_as_float(uh23 << 16);
    r23.y = f[3] - __uint_as_float(uh23 & 0xffff0000u);
    __hip_bfloat162 l01 = __float22bfloat162_rn(r01);
    __hip_bfloat162 l23 = __float22bfloat162_rn(r23);
    hi[0] = uh01; hi[1] = uh23;
    lo[0] = *reinterpret_cast<uint32_t*>(&l01);
    lo[1] = *reinterpret_cast<uint32_t*>(&l23);
}

// Barrier that does NOT drain vmcnt (prefetch loads stay in flight).
__device__ __forceinline__ void lds_sync() {
    asm volatile("s_waitcnt lgkmcnt(0)" ::: "memory");
    __builtin_amdgcn_s_barrier();
    asm volatile("" ::: "memory");
}

// ---------------------------------------------------------------------------
__global__ void wt4_kernel(const float* __restrict__ w0, const float* __restrict__ w1,
                           const float* __restrict__ w2, const float* __restrict__ w3,
                           float* __restrict__ o0, float* __restrict__ o1,
                           float* __restrict__ o2, float* __restrict__ o3) {
    const float* w; float* o;
    switch (blockIdx.y) {
        case 0: w = w0; o = o0; break;
        case 1: w = w1; o = o1; break;
        case 2: w = w2; o = o2; break;
        default: w = w3; o = o3; break;
    }
    int i = blockIdx.x * 256 + threadIdx.x;
    if (i < 192 * 64) {
        int r = i / 64, k = i % 64;
        o[k * 192 + r] = w[i];
    }
}

// ---------------------------------------------------------------------------
// B = X @ W (fp32) -> tile-contiguous packed bf16 hi/lo:
//   Bpk[(k>>6)*8192 + part*4096 + (((k>>3)&7)*64 + c)*8 + (k&7)]
__global__ void __launch_bounds__(256) xw_kernel(const float* __restrict__ X,
                                                 const float* __restrict__ W,
                                                 uint16_t* __restrict__ Bpk) {
    __shared__ __align__(16) float sW[64 * 65];
    __shared__ __align__(16) float sX[64 * 65];
    const int t = threadIdx.x;
    const int rb = blockIdx.x * 64;
    for (int i = t; i < 4096; i += 256) {
        int rr = i >> 6, cc = i & 63;
        sW[rr * 65 + cc] = W[i];
        sX[rr * 65 + cc] = X[(size_t)rb * 64 + i];
    }
    __syncthreads();
    const int r = t & 63;
    const int c0 = (t >> 6) * 16;
    float acc[16];
#pragma unroll
    for (int i = 0; i < 16; i++) acc[i] = 0.f;
    for (int k = 0; k < 64; k++) {
        float xv = sX[r * 65 + k];
#pragma unroll
        for (int i = 0; i < 16; i++) acc[i] += xv * sW[k * 65 + c0 + i];
    }
    const int j = rb + r;
    const size_t base = (size_t)(j >> 6) * 8192 + (size_t)((j >> 3) & 7) * 512 + (j & 7);
#pragma unroll
    for (int i = 0; i < 16; i++) {
        uint16_t hb, lb;
        split_bf(acc[i], hb, lb);
        size_t idx = base + (size_t)(c0 + i) * 8;
        Bpk[idx] = hb;
        Bpk[idx + 4096] = lb;
    }
}

// ---------------------------------------------------------------------------
// partial[kc] = adj[:, kchunk] @ B[kchunk, :]   (bf16 hi/lo, 3-MFMA)
// grid (192, KSPLIT), block 128 (2 waves). Block tile: 64 rows x 64 cols.
// Each WAVE owns 32 rows (2x16 MFMA row-tiles) -> B re-read 2x not 4x.
// A: wave-private LDS region, single-buffered (same-wave DS order => no WAR).
// B: shared, double-buffered. ONE lgkm-only barrier per tile; depth-2 reg
// prefetch rides across barriers (vmcnt never drained).
__global__ void __launch_bounds__(128, 2) spmm_kernel(
    const float* __restrict__ adj,
    const uint16_t* __restrict__ Bpk,
    float* __restrict__ partial,
    int ktiles, int rev) {
    __shared__ __align__(16) uint16_t sAhi[4096];   // [64 rows][64k] swizzled, 8 KB
    __shared__ __align__(16) uint16_t sAlo[4096];
    __shared__ __align__(16) uint16_t sB0[8192];    // 16 KB: hi(4096)+lo(4096)
    __shared__ __align__(16) uint16_t sB1[8192];
    const int t = threadIdx.x;
    const int rb = blockIdx.x;
    const int kc = blockIdx.y;
    const int tile0 = kc * ktiles;
    const int wave = t >> 6, lane = t & 63;
    const int srow4 = lane >> 4;      // 0..3
    const int skk = (lane & 15) * 4;  // 0..60
    const float* aptr = adj + (size_t)rb * 64 * NN;
    const int kq = lane >> 4;         // 0..3

    f32x4 acc[2][4];
#pragma unroll
    for (int rt = 0; rt < 2; rt++)
#pragma unroll
        for (int ct = 0; ct < 4; ct++) {
            acc[rt][ct][0] = 0.f; acc[rt][ct][1] = 0.f;
            acc[rt][ct][2] = 0.f; acc[rt][ct][3] = 0.f;
        }

    f32x4 aR0[8], aR1[8];
    u16x8 bR0[8], bR1[8];

    auto tid2glob = [&](int i) { return tile0 + (rev ? (ktiles - 1 - i) : i); };

    // wave's A rows: wave*32 + i*4 + srow4 (i=0..7); 16B chunk at skk
    auto load_tile = [&](int tl, f32x4 (&aR)[8], u16x8 (&bR)[8]) {
        const float* ap = aptr + (size_t)tid2glob(tl) * 64 + skk;
#pragma unroll
        for (int i = 0; i < 8; ++i) {
            int row = wave * 32 + i * 4 + srow4;
            aR[i] = *(const f32x4*)(ap + (size_t)row * NN);
        }
        const u16x8* bsrc = (const u16x8*)(Bpk + (size_t)tid2glob(tl) * 8192);
#pragma unroll
        for (int i = 0; i < 8; ++i) bR[i] = bsrc[i * 128 + t];
    };

    auto stage_tile = [&](f32x4 (&aR)[8], u16x8 (&bR)[8], uint16_t* sB) {
#pragma unroll
        for (int i = 0; i < 8; ++i) {
            int row = wave * 32 + i * 4 + srow4;
            u32x2 hi, lo;
            split4_pk(aR[i], hi, lo);
            int off = row * 128 + (((skk >> 3) ^ (row & 7)) << 4) + ((skk & 7) << 1);
            *(u32x2*)((char*)sAhi + off) = hi;
            *(u32x2*)((char*)sAlo + off) = lo;
        }
#pragma unroll
        for (int i = 0; i < 8; ++i) ((u16x8*)sB)[i * 128 + t] = bR[i];
    };

    auto compute_tile = [&](const uint16_t* sB) {
#pragma unroll
        for (int ks = 0; ks < 2; ++ks) {
            const int chunk = ks * 4 + kq;
            const int bko = chunk * 512;
#pragma unroll
            for (int rt = 0; rt < 2; ++rt) {
                const int arow = wave * 32 + rt * 16 + (lane & 15);
                const int aoff = arow * 128 + ((chunk ^ (arow & 7)) << 4);
                bfrag8 ahi = *(const bfrag8*)((const char*)sAhi + aoff);
                bfrag8 alo = *(const bfrag8*)((const char*)sAlo + aoff);
#pragma unroll
                for (int ct = 0; ct < 4; ++ct) {
                    int col = ct * 16 + (lane & 15);
                    bfrag8 bh = *(const bfrag8*)&sB[bko + col * 8];
                    bfrag8 bl = *(const bfrag8*)&sB[4096 + bko + col * 8];
                    acc[rt][ct] = __builtin_amdgcn_mfma_f32_16x16x32_bf16(ahi, bh, acc[rt][ct], 0, 0, 0);
                    acc[rt][ct] = __builtin_amdgcn_mfma_f32_16x16x32_bf16(alo, bh, acc[rt][ct], 0, 0, 0);
                    acc[rt][ct] = __builtin_amdgcn_mfma_f32_16x16x32_bf16(ahi, bl, acc[rt][ct], 0, 0, 0);
                }
            }
        }
    };

    // prologue: two tiles in flight; stage tile 0; barrier
    load_tile(0, aR0, bR0);
    load_tile(1, aR1, bR1);
    stage_tile(aR0, bR0, sB0);     // counted vmcnt wait on tile-0 regs only
    lds_sync();

    for (int tl = 0; tl < ktiles; tl += 2) {
        // tile tl (even): B in sB0
        compute_tile(sB0);
        if (tl + 1 < ktiles) stage_tile(aR1, bR1, sB1);
        if (tl + 2 < ktiles) load_tile(tl + 2, aR0, bR0);
        lds_sync();
        // tile tl+1 (odd): B in sB1
        if (tl + 1 < ktiles) {
            compute_tile(sB1);
            if (tl + 2 < ktiles) stage_tile(aR0, bR0, sB0);
            if (tl + 3 < ktiles) load_tile(tl + 3, aR1, bR1);
            lds_sync();
        }
    }

    // epilogue: C layout (m89-verified): col = lane&15, row = (lane>>4)*4 + reg
    float* pout = partial + (size_t)kc * ((size_t)NN * 64);
    const int ocol = lane & 15;
#pragma unroll
    for (int rt = 0; rt < 2; ++rt) {
        const int orow = rb * 64 + wave * 32 + rt * 16 + (lane >> 4) * 4;
#pragma unroll
        for (int ct = 0; ct < 4; ++ct) {
#pragma unroll
            for (int r = 0; r < 4; ++r) {
                pout[(size_t)(orow + r) * 64 + ct * 16 + ocol] = acc[rt][ct][r];
            }
        }
    }
}

// ---------------------------------------------------------------------------
// Fused: m = sum(partials); GRUCell(m, x); relu; write fp32 output.
__global__ void __launch_bounds__(256, 4) gru_kernel(
    const float* __restrict__ partial, int ksplit,
    const float* __restrict__ Xin,
    const float* __restrict__ wtih,  // [64][192]
    const float* __restrict__ wthh,  // [64][192]
    const float* __restrict__ bih,
    const float* __restrict__ bhh,
    float* __restrict__ hout) {
    __shared__ __align__(16) float sM[32 * 64];
    __shared__ __align__(16) float sX[32 * 64];
    const int t = threadIdx.x;
    const int nb = blockIdx.x * 32;
    {
        size_t g0 = (size_t)nb * 64 + (size_t)t * 8;
        f32x4 s0, s1;
        {
            const f32x4* p0 = (const f32x4*)(partial + g0);
            s0 = p0[0]; s1 = p0[1];
        }
        for (int p = 1; p < ksplit; p++) {
            const f32x4* pp = (const f32x4*)(partial + (size_t)p * ((size_t)NN * 64) + g0);
            f32x4 a = pp[0], b = pp[1];
#pragma unroll
            for (int q = 0; q < 4; q++) { s0[q] += a[q]; s1[q] += b[q]; }
        }
        *(f32x4*)&sM[t * 8] = s0;
        *(f32x4*)&sM[t * 8 + 4] = s1;
        const f32x4* px = (const f32x4*)(Xin + g0);
        *(f32x4*)&sX[t * 8] = px[0];
        *(f32x4*)&sX[t * 8 + 4] = px[1];
    }
    __syncthreads();
    const int wave = t >> 6, lane = t & 63;
    const int nodebase = wave * 8;
    float a_ir[8], a_iz[8], a_in[8], a_hr[8], a_hz[8], a_hn[8];
#pragma unroll
    for (int n = 0; n < 8; n++) {
        a_ir[n] = 0.f; a_iz[n] = 0.f; a_in[n] = 0.f;
        a_hr[n] = 0.f; a_hz[n] = 0.f; a_hn[n] = 0.f;
    }
    for (int k = 0; k < 64; k++) {
        float w0 = wtih[k * 192 + lane];
        float w1 = wtih[k * 192 + 64 + lane];
        float w2 = wtih[k * 192 + 128 + lane];
        float w3 = wthh[k * 192 + lane];
        float w4 = wthh[k * 192 + 64 + lane];
        float w5 = wthh[k * 192 + 128 + lane];
#pragma unroll
        for (int n = 0; n < 8; n++) {
            float mv = sM[(nodebase + n) * 64 + k];
            float xv = sX[(nodebase + n) * 64 + k];
            a_ir[n] += w0 * mv; a_iz[n] += w1 * mv; a_in[n] += w2 * mv;
            a_hr[n] += w3 * xv; a_hz[n] += w4 * xv; a_hn[n] += w5 * xv;
        }
    }
    const float b0 = bih[lane], b1 = bih[64 + lane], b2 = bih[128 + lane];
    const float b3 = bhh[lane], b4 = bhh[64 + lane], b5 = bhh[128 + lane];
#pragma unroll
    for (int n = 0; n < 8; n++) {
        float ir = a_ir[n] + b0, iz = a_iz[n] + b1, inn = a_in[n] + b2;
        float hr = a_hr[n] + b3, hz = a_hz[n] + b4, hn = a_hn[n] + b5;
        float r = 1.f / (1.f + __expf(-(ir + hr)));
        float z = 1.f / (1.f + __expf(-(iz + hz)));
        float nt = tanhf(inn + r * hn);
        float xv = sX[(nodebase + n) * 64 + lane];
        float o = (1.f - z) * nt + z * xv;
        o = fmaxf(o, 0.f);
        size_t oi = (size_t)(nb + nodebase + n) * 64 + lane;
        hout[oi] = o;
    }
}

// ---------------------------------------------------------------------------
extern "C" void kernel_launch(void* const* d_in, const int* in_sizes, int n_in,
                              void* d_out, int out_size, void* d_ws, size_t ws_size,
                              hipStream_t stream) {
    const float* x    = (const float*)d_in[0];
    const float* adj  = (const float*)d_in[1];
    const float* W1   = (const float*)d_in[2];
    const float* wih1 = (const float*)d_in[3];
    const float* whh1 = (const float*)d_in[4];
    const float* bih1 = (const float*)d_in[5];
    const float* bhh1 = (const float*)d_in[6];
    const float* W2   = (const float*)d_in[7];
    const float* wih2 = (const float*)d_in[8];
    const float* whh2 = (const float*)d_in[9];
    const float* bih2 = (const float*)d_in[10];
    const float* bhh2 = (const float*)d_in[11];
    float* out = (float*)d_out;   // reference output dtype is float32

    char* p = (char*)d_ws;
    float* wtih1 = (float*)p; p += (size_t)192 * 64 * 4;
    float* wthh1 = (float*)p; p += (size_t)192 * 64 * 4;
    float* wtih2 = (float*)p; p += (size_t)192 * 64 * 4;
    float* wthh2 = (float*)p; p += (size_t)192 * 64 * 4;
    float* h     = (float*)p; p += (size_t)NN * 64 * 4;
    uint16_t* Bpk = (uint16_t*)p; p += (size_t)NN * 64 * 2 * 2;  // hi+lo packed
    float* partial = (float*)p;
    size_t used = (size_t)(p - (char*)d_ws);
    size_t unit = (size_t)NN * 64 * 4;

    int ksplit = 1;
    const int opts[3] = {4, 2, 1};
    for (int i = 0; i < 3; i++) {
        if (used + (size_t)opts[i] * unit <= ws_size) { ksplit = opts[i]; break; }
    }
    int ktiles = 192 / ksplit;

    wt4_kernel<<<dim3(48, 4), 256, 0, stream>>>(wih1, whh1, wih2, whh2,
                                                wtih1, wthh1, wtih2, wthh2);

    // layer 1 (forward K order)
    xw_kernel<<<192, 256, 0, stream>>>(x, W1, Bpk);
    spmm_kernel<<<dim3(192, ksplit), 128, 0, stream>>>(adj, Bpk, partial, ktiles, 0);
    gru_kernel<<<384, 256, 0, stream>>>(partial, ksplit, x, wtih1, wthh1, bih1, bhh1, h);
    // layer 2 (reverse K order — boustrophedon: reuse adj tail still in L3)
    xw_kernel<<<192, 256, 0, stream>>>(h, W2, Bpk);
    spmm_kernel<<<dim3(192, ksplit), 128, 0, stream>>>(adj, Bpk, partial, ktiles, 1);
    gru_kernel<<<384, 256, 0, stream>>>(partial, ksplit, h, wtih2, wthh2, bih2, bhh2, out);
}